// Round 1
// baseline (754.185 us; speedup 1.0000x reference)
//
#include <hip/hip_runtime.h>
#include <stdint.h>
#include <stddef.h>

typedef __attribute__((ext_vector_type(4))) float  f32x4;
typedef __attribute__((ext_vector_type(4))) float  float4v;
typedef __attribute__((ext_vector_type(8))) short  s16x8;
typedef __attribute__((ext_vector_type(4))) short  s16x4;

#define DEV static __device__ __forceinline__

DEV short f2bf(float f) {                 // RNE fp32 -> bf16 (inputs finite)
  unsigned u = __builtin_bit_cast(unsigned, f);
  u = u + 0x7fffu + ((u >> 16) & 1u);
  return (short)(u >> 16);
}
DEV float bf2f(short s) {
  unsigned u = ((unsigned)(unsigned short)s) << 16;
  return __builtin_bit_cast(float, u);
}
DEV void gload16(const void* g, void* l) { // async global->LDS, 16B/lane, dest = base + lane*16
  __builtin_amdgcn_global_load_lds((const __attribute__((address_space(1))) void*)g,
                                   (__attribute__((address_space(3))) void*)l, 16, 0, 0);
}

// ---------------- fp32 -> bf16 converts ----------------
__global__ void cvt4(const float4v* __restrict__ src, s16x4* __restrict__ dst, int n4) {
  int i = blockIdx.x * 256 + threadIdx.x;
  if (i >= n4) return;
  float4v v = src[i];
  s16x4 o; o.x = f2bf(v.x); o.y = f2bf(v.y); o.z = f2bf(v.z); o.w = f2bf(v.w);
  dst[i] = o;
}
// duplicate each element (for hi/lo split K=2048 GEMM): dst[2i]=dst[2i+1]=bf16(src[i])
__global__ void cvt_dup(const float4v* __restrict__ src, s16x8* __restrict__ dst, int n4) {
  int i = blockIdx.x * 256 + threadIdx.x;
  if (i >= n4) return;
  float4v v = src[i];
  s16x8 o;
  o[0] = f2bf(v.x); o[1] = o[0];
  o[2] = f2bf(v.y); o[3] = o[2];
  o[4] = f2bf(v.z); o[5] = o[4];
  o[6] = f2bf(v.w); o[7] = o[6];
  dst[i] = o;
}

// ---------------- GEMM: C[M=8192][N=1024] = A[M][KDIM] @ B[1024][KDIM]^T + bias ----------------
// EPI: 0 = bf16 C;  1 = f32 C;  2 = bf16 C written per-head-transposed (Vt[b,h,d,kv])
// 128x128 tile, BK=32, 4 waves (each 64x64 = 4x4 frags), double-buffered LDS,
// global_load_lds staging with pre-swizzled source (chunk ^= (row>>1)&3).
template <int EPI, int KDIM>
__global__ __launch_bounds__(256) void gemm_nt(const short* __restrict__ A,
                                               const short* __restrict__ Bw,
                                               const float* __restrict__ bias,
                                               void* __restrict__ Cp) {
  __shared__ __attribute__((aligned(16))) short As[2][128 * 32];
  __shared__ __attribute__((aligned(16))) short Bs[2][128 * 32];
  const int tid = threadIdx.x;
  const int wg  = blockIdx.x;
  const int swz = (wg & 7) * ((int)gridDim.x >> 3) + (wg >> 3);  // XCD-aware (512 % 8 == 0)
  const int bm = swz >> 3, bn = swz & 7;
  const int mbase = bm * 128, nbase = bn * 128;
  const int w = tid >> 6, l = tid & 63;
  const int wm = w >> 1, wn = w & 1;

  auto stage = [&](int buf, int kt) {
#pragma unroll
    for (int j = 0; j < 2; ++j) {
      int cb  = w * 128 + j * 64;       // wave-uniform chunk base
      int ci  = cb + l;                 // this lane's chunk
      int row = ci >> 2, cc = ci & 3;
      int c   = cc ^ ((row >> 1) & 3);  // inverse-swizzled SOURCE chunk
      gload16(A  + (size_t)(mbase + row) * KDIM + kt * 32 + c * 8, &As[buf][cb * 8]);
      gload16(Bw + (size_t)(nbase + row) * KDIM + kt * 32 + c * 8, &Bs[buf][cb * 8]);
    }
  };

  f32x4 acc[4][4];
#pragma unroll
  for (int i = 0; i < 4; ++i)
#pragma unroll
    for (int j = 0; j < 4; ++j) acc[i][j] = (f32x4){0.f, 0.f, 0.f, 0.f};

  const int KSTEPS = KDIM / 32;
  stage(0, 0);
  for (int kt = 0; kt < KSTEPS; ++kt) {
    __syncthreads();                       // drains vmcnt: buf[kt&1] ready
    if (kt + 1 < KSTEPS) stage((kt + 1) & 1, kt + 1);
    const int buf = kt & 1;
    s16x8 af[4], bf[4];
    const int g = l >> 4;
#pragma unroll
    for (int i = 0; i < 4; ++i) {
      int ra = wm * 64 + i * 16 + (l & 15);
      int pa = g ^ ((ra >> 1) & 3);
      af[i] = *(const s16x8*)&As[buf][ra * 32 + pa * 8];
      int rb = wn * 64 + i * 16 + (l & 15);
      int pb = g ^ ((rb >> 1) & 3);
      bf[i] = *(const s16x8*)&Bs[buf][rb * 32 + pb * 8];
    }
#pragma unroll
    for (int i = 0; i < 4; ++i)
#pragma unroll
      for (int j = 0; j < 4; ++j)
        acc[i][j] = __builtin_amdgcn_mfma_f32_16x16x32_bf16(af[i], bf[j], acc[i][j], 0, 0, 0);
  }

  // epilogue
  float bj[4];
#pragma unroll
  for (int j = 0; j < 4; ++j) bj[j] = bias[nbase + wn * 64 + j * 16 + (l & 15)];
#pragma unroll
  for (int i = 0; i < 4; ++i) {
#pragma unroll
    for (int j = 0; j < 4; ++j) {
      int m0 = mbase + wm * 64 + i * 16 + (l >> 4) * 4;
      int n  = nbase + wn * 64 + j * 16 + (l & 15);
      if constexpr (EPI == 0) {
        short* C16 = (short*)Cp;
#pragma unroll
        for (int jj = 0; jj < 4; ++jj)
          C16[(size_t)(m0 + jj) * 1024 + n] = f2bf(acc[i][j][jj] + bj[j]);
      } else if constexpr (EPI == 1) {
        float* Cf = (float*)Cp;
#pragma unroll
        for (int jj = 0; jj < 4; ++jj)
          Cf[(size_t)(m0 + jj) * 1024 + n] = acc[i][j][jj] + bj[j];
      } else {  // per-head transposed V:  Vt[(b*1024 + n)*1024 + kv], n = h*64+d
        short* C16 = (short*)Cp;
        int bb = m0 >> 10, kv = m0 & 1023;
        s16x4 o;
#pragma unroll
        for (int jj = 0; jj < 4; ++jj) o[jj] = f2bf(acc[i][j][jj] + bj[j]);
        *(s16x4*)&C16[((size_t)(bb * 1024 + n)) * 1024 + kv] = o;
      }
    }
  }
}

// ---------------- fused attention ----------------
// grid (32 qtiles, 8 batch), 512 thr (8 waves). 32 q-rows/block, loops 16 heads.
// Per head: S[32][1024] via MFMA (K-tiles of 64 kv staged in LDS, XOR-swizzled),
// wave-parallel softmax (16 threads/row), head-mean accumulated in registers,
// PV via MFMA with Vt tiles, output written as hi/lo bf16 pairs (K=2048 downstream).
__global__ __launch_bounds__(512) void attn_fused(const short* __restrict__ Qp,
                                                  const short* __restrict__ Kp,
                                                  const short* __restrict__ Vt,
                                                  const float* __restrict__ cluster,
                                                  short* __restrict__ AO2,
                                                  float* __restrict__ Amean) {
  const int SP = 1028;  // S row stride (floats): 4 mod 32 -> conflict-free PV A-reads
  __shared__ __attribute__((aligned(16))) float S[32 * 1028];   // 128.5 KB
  __shared__ __attribute__((aligned(16))) short KV[2][64 * 64]; // 16 KB
  const int tid = threadIdx.x;
  const int b = blockIdx.y, qt = blockIdx.x;
  const int qbase = qt * 32;
  const int w = tid >> 6, l = tid & 63;
  const int qh = w >> 2, sub = w & 3;     // A: kv-subtile / C: d-subtile
  const int r = tid >> 4, li = tid & 15;  // softmax: 16 threads per q-row
  const float scale = 0.125f;             // 1/sqrt(64)

  auto stageK = [&](int buf, int t, int h) {
    int row = tid >> 3, cc = tid & 7;
    int c = cc ^ (row & 7);
    gload16(Kp + ((size_t)(b * 1024 + t * 64 + row)) * 1024 + h * 64 + c * 8,
            &KV[buf][(tid >> 6) * 512]);
  };
  auto stageV = [&](int buf, int t, int h) {
    int row = tid >> 3, cc = tid & 7;   // row = d (0..63)
    int c = cc ^ (row & 7);
    gload16(Vt + ((size_t)((b * 16 + h) * 64 + row)) * 1024 + t * 64 + c * 8,
            &KV[buf][(tid >> 6) * 512]);
  };

  // per-thread cluster row slice + head-mean accumulator (same (r,c) ownership every head)
  float clv[64], macc[64];
  {
    const float* cl = cluster + ((size_t)(b * 1024 + qbase + r)) * 1024 + li;
#pragma unroll
    for (int i = 0; i < 64; ++i) { clv[i] = cl[16 * i]; macc[i] = 0.f; }
  }

  for (int h = 0; h < 16; ++h) {
    // Q fragments for this head (A-operand rows = q)
    s16x8 aq[2];
    {
      size_t base = ((size_t)(b * 1024 + qbase + qh * 16 + (l & 15))) * 1024 + h * 64 + (l >> 4) * 8;
      aq[0] = *(const s16x8*)&Qp[base];
      aq[1] = *(const s16x8*)&Qp[base + 32];
    }

    // ---- phase A: S = Q @ K^T ----
    stageK(0, 0, h);
    for (int t = 0; t < 16; ++t) {
      __syncthreads();
      if (t < 15) stageK((t + 1) & 1, t + 1, h);
      const int buf = t & 1;
      f32x4 sacc = (f32x4){0.f, 0.f, 0.f, 0.f};
#pragma unroll
      for (int ks = 0; ks < 2; ++ks) {
        int row = sub * 16 + (l & 15);
        int ch = ks * 4 + (l >> 4);
        int phys = ch ^ (row & 7);
        s16x8 bk = *(const s16x8*)&KV[buf][row * 64 + phys * 8];
        sacc = __builtin_amdgcn_mfma_f32_16x16x32_bf16(aq[ks], bk, sacc, 0, 0, 0);
      }
      int col = t * 64 + sub * 16 + (l & 15);
      int q0 = qh * 16 + (l >> 4) * 4;
#pragma unroll
      for (int jj = 0; jj < 4; ++jj) S[(q0 + jj) * SP + col] = sacc[jj];
    }
    __syncthreads();

    // ---- softmax (row-wise over 1024), accumulate head-mean in regs ----
    {
      float v[64];
      float m = -3.0e38f;
#pragma unroll
      for (int i = 0; i < 64; ++i) {
        float x = S[r * SP + li + 16 * i] * scale + clv[i];
        v[i] = x;
        m = fmaxf(m, x);
      }
#pragma unroll
      for (int off = 8; off >= 1; off >>= 1) m = fmaxf(m, __shfl_xor(m, off, 16));
      float sum = 0.f;
#pragma unroll
      for (int i = 0; i < 64; ++i) {
        float p = exp2f((v[i] - m) * 1.4426950408889634f);
        v[i] = p; sum += p;
      }
#pragma unroll
      for (int off = 8; off >= 1; off >>= 1) sum += __shfl_xor(sum, off, 16);
      float inv = 1.0f / sum;
#pragma unroll
      for (int i = 0; i < 64; ++i) {
        float p = v[i] * inv;
        S[r * SP + li + 16 * i] = p;
        macc[i] += p;
      }
    }
    __syncthreads();

    // ---- phase C: O = P @ V ----
    stageV(0, 0, h);
    f32x4 oacc = (f32x4){0.f, 0.f, 0.f, 0.f};
    for (int t = 0; t < 16; ++t) {
      __syncthreads();
      if (t < 15) stageV((t + 1) & 1, t + 1, h);
      const int buf = t & 1;
#pragma unroll
      for (int ks = 0; ks < 2; ++ks) {
        int kv = t * 64 + ks * 32 + (l >> 4) * 8;
        const float* ps = &S[(qh * 16 + (l & 15)) * SP + kv];
        f32x4 p0 = *(const f32x4*)ps;
        f32x4 p1 = *(const f32x4*)(ps + 4);
        s16x8 pa;
        pa[0] = f2bf(p0[0]); pa[1] = f2bf(p0[1]); pa[2] = f2bf(p0[2]); pa[3] = f2bf(p0[3]);
        pa[4] = f2bf(p1[0]); pa[5] = f2bf(p1[1]); pa[6] = f2bf(p1[2]); pa[7] = f2bf(p1[3]);
        int rowv = sub * 16 + (l & 15);
        int ch = ks * 4 + (l >> 4);
        int phys = ch ^ (rowv & 7);
        s16x8 bv = *(const s16x8*)&KV[buf][rowv * 64 + phys * 8];
        oacc = __builtin_amdgcn_mfma_f32_16x16x32_bf16(pa, bv, oacc, 0, 0, 0);
      }
    }
    // write O as hi/lo bf16 pairs into AO2[8192][2048]
    {
      int q0 = qh * 16 + (l >> 4) * 4;
      int d = sub * 16 + (l & 15);
#pragma unroll
      for (int jj = 0; jj < 4; ++jj) {
        float x = oacc[jj];
        short hi = f2bf(x);
        short lo = f2bf(x - bf2f(hi));
        size_t base = ((size_t)(b * 1024 + qbase + q0 + jj)) * 2048 + (size_t)(h * 64 + d) * 2;
        AO2[base] = hi;
        AO2[base + 1] = lo;
      }
    }
    __syncthreads();  // protect S and KV before next head
  }

  // head-mean output
#pragma unroll
  for (int i = 0; i < 64; ++i)
    Amean[((size_t)(b * 1024 + qbase + r)) * 1024 + li + 16 * i] = macc[i] * 0.0625f;
}

// ---------------- launch ----------------
extern "C" void kernel_launch(void* const* d_in, const int* in_sizes, int n_in,
                              void* d_out, int out_size, void* d_ws, size_t ws_size,
                              hipStream_t stream) {
  (void)in_sizes; (void)n_in; (void)out_size; (void)ws_size;
  const float* query     = (const float*)d_in[0];
  const float* key_value = (const float*)d_in[1];
  const float* cluster   = (const float*)d_in[2];
  const float* Wq = (const float*)d_in[3];
  const float* bq = (const float*)d_in[4];
  const float* Wk = (const float*)d_in[5];
  const float* bk = (const float*)d_in[6];
  const float* Wv = (const float*)d_in[7];
  const float* bv = (const float*)d_in[8];
  const float* Wo = (const float*)d_in[9];
  const float* bo = (const float*)d_in[10];

  char* ws = (char*)d_ws;
  short* qb  = (short*)(ws);                  // [8192][1024] bf16 (16 MB)
  short* kvb = (short*)(ws + 16777216);       // [8192][1024]
  short* Wqb = (short*)(ws + 33554432);       // [1024][1024]
  short* Wkb = (short*)(ws + 35651584);
  short* Wvb = (short*)(ws + 37748736);
  short* Wo2 = (short*)(ws + 39845888);       // [1024][2048] duplicated
  short* Qp  = (short*)(ws + 44040192);       // [8192][1024]
  short* Kp  = (short*)(ws + 60817408);       // [8192][1024]
  short* Vtp = (short*)(ws + 77594624);       // [b][h][64][1024]
  short* AO2 = (short*)(ws + 94371840);       // [8192][2048] hi/lo pairs (32 MB)

  float* out_uq = (float*)d_out;              // updated_query [8,1024,1024]
  float* out_am = (float*)d_out + 8388608;    // attn_matrix   [8,1024,1024]

  cvt4<<<8192, 256, 0, stream>>>((const float4v*)query,     (s16x4*)qb,  2097152);
  cvt4<<<8192, 256, 0, stream>>>((const float4v*)key_value, (s16x4*)kvb, 2097152);
  cvt4<<<1024, 256, 0, stream>>>((const float4v*)Wq, (s16x4*)Wqb, 262144);
  cvt4<<<1024, 256, 0, stream>>>((const float4v*)Wk, (s16x4*)Wkb, 262144);
  cvt4<<<1024, 256, 0, stream>>>((const float4v*)Wv, (s16x4*)Wvb, 262144);
  cvt_dup<<<1024, 256, 0, stream>>>((const float4v*)Wo, (s16x8*)Wo2, 262144);

  gemm_nt<0, 1024><<<512, 256, 0, stream>>>(qb,  Wqb, bq, Qp);
  gemm_nt<0, 1024><<<512, 256, 0, stream>>>(kvb, Wkb, bk, Kp);
  gemm_nt<2, 1024><<<512, 256, 0, stream>>>(kvb, Wvb, bv, Vtp);

  attn_fused<<<dim3(32, 8), 512, 0, stream>>>(Qp, Kp, Vtp, cluster, AO2, out_am);

  gemm_nt<1, 2048><<<512, 256, 0, stream>>>(AO2, Wo2, bo, out_uq);
}

// Round 2
// 551.099 us; speedup vs baseline: 1.3685x; 1.3685x over previous
//
#include <hip/hip_runtime.h>
#include <stdint.h>
#include <stddef.h>

typedef __attribute__((ext_vector_type(4))) float  f32x4;
typedef __attribute__((ext_vector_type(4))) float  float4v;
typedef __attribute__((ext_vector_type(8))) short  s16x8;
typedef __attribute__((ext_vector_type(4))) short  s16x4;
typedef __attribute__((ext_vector_type(2))) unsigned int u32x2;

#define DEV static __device__ __forceinline__

DEV short f2bf(float f) {                 // RNE fp32 -> bf16 (inputs finite)
  unsigned u = __builtin_bit_cast(unsigned, f);
  u = u + 0x7fffu + ((u >> 16) & 1u);
  return (short)(u >> 16);
}
DEV float bf2f(short s) {
  unsigned u = ((unsigned)(unsigned short)s) << 16;
  return __builtin_bit_cast(float, u);
}
DEV f32x4 vmax4(f32x4 a, f32x4 b) {
  f32x4 r;
  r[0] = fmaxf(a[0], b[0]); r[1] = fmaxf(a[1], b[1]);
  r[2] = fmaxf(a[2], b[2]); r[3] = fmaxf(a[3], b[3]);
  return r;
}
DEV void gload16(const void* g, void* l) { // async global->LDS, 16B/lane, dest = base + lane*16
  __builtin_amdgcn_global_load_lds((const __attribute__((address_space(1))) void*)g,
                                   (__attribute__((address_space(3))) void*)l, 16, 0, 0);
}

// ---------------- fp32 -> bf16 converts ----------------
__global__ void cvt4(const float4v* __restrict__ src, s16x4* __restrict__ dst, int n4) {
  int i = blockIdx.x * 256 + threadIdx.x;
  if (i >= n4) return;
  float4v v = src[i];
  s16x4 o; o.x = f2bf(v.x); o.y = f2bf(v.y); o.z = f2bf(v.z); o.w = f2bf(v.w);
  dst[i] = o;
}
// duplicate each element (for hi/lo split K=2048 GEMM): dst[2i]=dst[2i+1]=bf16(src[i])
__global__ void cvt_dup(const float4v* __restrict__ src, s16x8* __restrict__ dst, int n4) {
  int i = blockIdx.x * 256 + threadIdx.x;
  if (i >= n4) return;
  float4v v = src[i];
  s16x8 o;
  o[0] = f2bf(v.x); o[1] = o[0];
  o[2] = f2bf(v.y); o[3] = o[2];
  o[4] = f2bf(v.z); o[5] = o[4];
  o[6] = f2bf(v.w); o[7] = o[6];
  dst[i] = o;
}

// ---------------- GEMM: C[M=8192][N=1024] = A[M][KDIM] @ B[1024][KDIM]^T + bias ----------------
// EPI: 0 = bf16 C;  1 = f32 C;  2 = bf16 C written per-head-transposed (Vt[b,h,d,kv])
template <int EPI, int KDIM>
__global__ __launch_bounds__(256) void gemm_nt(const short* __restrict__ A,
                                               const short* __restrict__ Bw,
                                               const float* __restrict__ bias,
                                               void* __restrict__ Cp) {
  __shared__ __attribute__((aligned(16))) short As[2][128 * 32];
  __shared__ __attribute__((aligned(16))) short Bs[2][128 * 32];
  const int tid = threadIdx.x;
  const int wg  = blockIdx.x;
  const int swz = (wg & 7) * ((int)gridDim.x >> 3) + (wg >> 3);  // XCD-aware (512 % 8 == 0)
  const int bm = swz >> 3, bn = swz & 7;
  const int mbase = bm * 128, nbase = bn * 128;
  const int w = tid >> 6, l = tid & 63;
  const int wm = w >> 1, wn = w & 1;

  auto stage = [&](int buf, int kt) {
#pragma unroll
    for (int j = 0; j < 2; ++j) {
      int cb  = w * 128 + j * 64;       // wave-uniform chunk base
      int ci  = cb + l;                 // this lane's chunk
      int row = ci >> 2, cc = ci & 3;
      int c   = cc ^ ((row >> 1) & 3);  // inverse-swizzled SOURCE chunk
      gload16(A  + (size_t)(mbase + row) * KDIM + kt * 32 + c * 8, &As[buf][cb * 8]);
      gload16(Bw + (size_t)(nbase + row) * KDIM + kt * 32 + c * 8, &Bs[buf][cb * 8]);
    }
  };

  f32x4 acc[4][4];
#pragma unroll
  for (int i = 0; i < 4; ++i)
#pragma unroll
    for (int j = 0; j < 4; ++j) acc[i][j] = (f32x4){0.f, 0.f, 0.f, 0.f};

  const int KSTEPS = KDIM / 32;
  stage(0, 0);
  for (int kt = 0; kt < KSTEPS; ++kt) {
    __syncthreads();                       // drains vmcnt: buf[kt&1] ready
    if (kt + 1 < KSTEPS) stage((kt + 1) & 1, kt + 1);
    const int buf = kt & 1;
    s16x8 af[4], bf[4];
    const int g = l >> 4;
#pragma unroll
    for (int i = 0; i < 4; ++i) {
      int ra = wm * 64 + i * 16 + (l & 15);
      int pa = g ^ ((ra >> 1) & 3);
      af[i] = *(const s16x8*)&As[buf][ra * 32 + pa * 8];
      int rb = wn * 64 + i * 16 + (l & 15);
      int pb = g ^ ((rb >> 1) & 3);
      bf[i] = *(const s16x8*)&Bs[buf][rb * 32 + pb * 8];
    }
#pragma unroll
    for (int i = 0; i < 4; ++i)
#pragma unroll
      for (int j = 0; j < 4; ++j)
        acc[i][j] = __builtin_amdgcn_mfma_f32_16x16x32_bf16(af[i], bf[j], acc[i][j], 0, 0, 0);
  }

  // epilogue
  float bj[4];
#pragma unroll
  for (int j = 0; j < 4; ++j) bj[j] = bias[nbase + wn * 64 + j * 16 + (l & 15)];
#pragma unroll
  for (int i = 0; i < 4; ++i) {
#pragma unroll
    for (int j = 0; j < 4; ++j) {
      int m0 = mbase + wm * 64 + i * 16 + (l >> 4) * 4;
      int n  = nbase + wn * 64 + j * 16 + (l & 15);
      if constexpr (EPI == 0) {
        short* C16 = (short*)Cp;
#pragma unroll
        for (int jj = 0; jj < 4; ++jj)
          C16[(size_t)(m0 + jj) * 1024 + n] = f2bf(acc[i][j][jj] + bj[j]);
      } else if constexpr (EPI == 1) {
        float* Cf = (float*)Cp;
#pragma unroll
        for (int jj = 0; jj < 4; ++jj)
          Cf[(size_t)(m0 + jj) * 1024 + n] = acc[i][j][jj] + bj[j];
      } else {  // per-head transposed V:  Vt[(b*1024 + n)*1024 + kv], n = h*64+d
        short* C16 = (short*)Cp;
        int bb = m0 >> 10, kv = m0 & 1023;
        s16x4 o;
#pragma unroll
        for (int jj = 0; jj < 4; ++jj) o[jj] = f2bf(acc[i][j][jj] + bj[j]);
        *(s16x4*)&C16[((size_t)(bb * 1024 + n)) * 1024 + kv] = o;
      }
    }
  }
}

// ---------------- fused attention v2 ----------------
// Block = (qtile of 32 rows, batch). 8 waves; wave w owns kv slice [128w, 128w+128).
// Swapped QK^T: mfma(K, Q) -> lane holds S[kv rows][q cols]: q = qcb*16 + (l&15),
// kv = wkv + kb*16 + 4*(l>>4) + jj  -> softmax rows are in-lane + shfl_xor(16,32).
// Cross-wave (m,l) combine via tiny LDS exchange. Normalized P -> shared LDS buffer
// (the q<->kv transpose), then PV: wave w owns output tile (qb=w>>2, db=w&3), full kv.
// Head-mean accumulated in registers (lane owns fixed (q,kv) cells across heads).
// Only 2 barriers per head. K/Q/V/cluster read straight from global (L2-hot).
__global__ __launch_bounds__(512, 2) void attn_fused2(const short* __restrict__ Qp,
                                                      const short* __restrict__ Kp,
                                                      const short* __restrict__ Vt,
                                                      const float* __restrict__ cluster,
                                                      short* __restrict__ AO2,
                                                      float* __restrict__ Amean) {
  constexpr int PSTR = 1032;  // bf16 row stride: 2064 B -> 516 words = 4 mod 32 (conflict-free b128 reads)
  __shared__ __attribute__((aligned(16))) short Pbuf[32 * PSTR];  // 66 KB
  __shared__ float mlbuf[32][8][2];                               // 2 KB
  const int tid = threadIdx.x;
  const int b = blockIdx.y, qt = blockIdx.x;
  const int w = tid >> 6, l = tid & 63;
  const int li = l & 15, g = l >> 4;
  const int wkv = w * 128;
  const int qb = w >> 2, db = w & 3;  // PV output tile
  const float scale = 0.125f;         // 1/sqrt(64)
  const float LOG2E = 1.4426950408889634f;

  const size_t qrow0 = (size_t)(b * 1024 + qt * 32);
  const size_t krow0 = (size_t)(b * 1024);

  float macc[2][8][4];
#pragma unroll
  for (int a = 0; a < 2; ++a)
#pragma unroll
    for (int kb = 0; kb < 8; ++kb)
#pragma unroll
      for (int jj = 0; jj < 4; ++jj) macc[a][kb][jj] = 0.f;

  for (int h = 0; h < 16; ++h) {
    // ---- QK^T (swapped): acc[qcb][kb] over kv slice ----
    s16x8 qf[2][2];
#pragma unroll
    for (int qcb = 0; qcb < 2; ++qcb)
#pragma unroll
      for (int kc = 0; kc < 2; ++kc)
        qf[qcb][kc] = *(const s16x8*)&Qp[(qrow0 + qcb * 16 + li) * 1024 + h * 64 + kc * 32 + g * 8];

    f32x4 acc[2][8];
#pragma unroll
    for (int a = 0; a < 2; ++a)
#pragma unroll
      for (int kb = 0; kb < 8; ++kb) acc[a][kb] = (f32x4){0.f, 0.f, 0.f, 0.f};

#pragma unroll
    for (int half = 0; half < 2; ++half) {
      s16x8 kf[8];
#pragma unroll
      for (int i = 0; i < 8; ++i) {
        int kb = half * 4 + (i >> 1), kc = i & 1;
        kf[i] = *(const s16x8*)&Kp[(krow0 + wkv + kb * 16 + li) * 1024 + h * 64 + kc * 32 + g * 8];
      }
#pragma unroll
      for (int i = 0; i < 8; ++i) {
        int kb = half * 4 + (i >> 1), kc = i & 1;
#pragma unroll
        for (int qcb = 0; qcb < 2; ++qcb)
          acc[qcb][kb] = __builtin_amdgcn_mfma_f32_16x16x32_bf16(kf[i], qf[qcb][kc], acc[qcb][kb], 0, 0, 0);
      }
    }

    // ---- per-wave softmax over the 128-kv slice ----
    float mw[2], lw[2];
#pragma unroll
    for (int qcb = 0; qcb < 2; ++qcb) {
      const float* clp = cluster + (qrow0 + qcb * 16 + li) * 1024 + wkv + 4 * g;
#pragma unroll
      for (int kb = 0; kb < 8; ++kb) {
        f32x4 cl = *(const f32x4*)(clp + kb * 16);
        acc[qcb][kb] = acc[qcb][kb] * scale + cl;
      }
      f32x4 mx = acc[qcb][0];
#pragma unroll
      for (int kb = 1; kb < 8; ++kb) mx = vmax4(mx, acc[qcb][kb]);
      float m = fmaxf(fmaxf(mx[0], mx[1]), fmaxf(mx[2], mx[3]));
      m = fmaxf(m, __shfl_xor(m, 16, 64));
      m = fmaxf(m, __shfl_xor(m, 32, 64));
      f32x4 s4 = (f32x4){0.f, 0.f, 0.f, 0.f};
#pragma unroll
      for (int kb = 0; kb < 8; ++kb) {
        f32x4 e;
#pragma unroll
        for (int jj = 0; jj < 4; ++jj) e[jj] = __builtin_amdgcn_exp2f((acc[qcb][kb][jj] - m) * LOG2E);
        acc[qcb][kb] = e;
        s4 += e;
      }
      float s = (s4[0] + s4[1]) + (s4[2] + s4[3]);
      s += __shfl_xor(s, 16, 64);
      s += __shfl_xor(s, 32, 64);
      mw[qcb] = m; lw[qcb] = s;
    }
    if (l < 16) {
#pragma unroll
      for (int qcb = 0; qcb < 2; ++qcb) {
        mlbuf[qcb * 16 + l][w][0] = mw[qcb];
        mlbuf[qcb * 16 + l][w][1] = lw[qcb];
      }
    }
    __syncthreads();  // barrier 1: (m,l) partials visible; prev head's Pbuf reads done

    // ---- combine + normalize + write P (bf16) + head-mean accumulate ----
#pragma unroll
    for (int qcb = 0; qcb < 2; ++qcb) {
      const int q = qcb * 16 + li;
      float m = mlbuf[q][0][0];
#pragma unroll
      for (int j = 1; j < 8; ++j) m = fmaxf(m, mlbuf[q][j][0]);
      float lt = 0.f;
#pragma unroll
      for (int j = 0; j < 8; ++j) lt += mlbuf[q][j][1] * __builtin_amdgcn_exp2f((mlbuf[q][j][0] - m) * LOG2E);
      const float c = __builtin_amdgcn_exp2f((mw[qcb] - m) * LOG2E) / lt;
#pragma unroll
      for (int kb = 0; kb < 8; ++kb) {
        f32x4 p = acc[qcb][kb] * c;
#pragma unroll
        for (int jj = 0; jj < 4; ++jj) macc[qcb][kb][jj] += p[jj];
        unsigned u0 = (unsigned)(unsigned short)f2bf(p[0]) | ((unsigned)(unsigned short)f2bf(p[1]) << 16);
        unsigned u1 = (unsigned)(unsigned short)f2bf(p[2]) | ((unsigned)(unsigned short)f2bf(p[3]) << 16);
        u32x2 uu; uu[0] = u0; uu[1] = u1;
        *(u32x2*)&Pbuf[q * PSTR + wkv + kb * 16 + 4 * g] = uu;
      }
    }
    __syncthreads();  // barrier 2: full P tile visible

    // ---- PV: wave tile (qb, db), full kv; 4 accumulator chains ----
    f32x4 o0 = (f32x4){0.f,0.f,0.f,0.f}, o1 = o0, o2 = o0, o3 = o0;
    const short* vbase = Vt + ((size_t)((b * 16 + h) * 64 + db * 16 + li)) * 1024 + g * 8;
    const short* pbase = &Pbuf[(qb * 16 + li) * PSTR + g * 8];
#pragma unroll
    for (int kc = 0; kc < 32; kc += 4) {
      s16x8 pf0 = *(const s16x8*)(pbase + (kc + 0) * 32);
      s16x8 vf0 = *(const s16x8*)(vbase + (kc + 0) * 32);
      s16x8 pf1 = *(const s16x8*)(pbase + (kc + 1) * 32);
      s16x8 vf1 = *(const s16x8*)(vbase + (kc + 1) * 32);
      s16x8 pf2 = *(const s16x8*)(pbase + (kc + 2) * 32);
      s16x8 vf2 = *(const s16x8*)(vbase + (kc + 2) * 32);
      s16x8 pf3 = *(const s16x8*)(pbase + (kc + 3) * 32);
      s16x8 vf3 = *(const s16x8*)(vbase + (kc + 3) * 32);
      o0 = __builtin_amdgcn_mfma_f32_16x16x32_bf16(pf0, vf0, o0, 0, 0, 0);
      o1 = __builtin_amdgcn_mfma_f32_16x16x32_bf16(pf1, vf1, o1, 0, 0, 0);
      o2 = __builtin_amdgcn_mfma_f32_16x16x32_bf16(pf2, vf2, o2, 0, 0, 0);
      o3 = __builtin_amdgcn_mfma_f32_16x16x32_bf16(pf3, vf3, o3, 0, 0, 0);
    }
    f32x4 of = (o0 + o1) + (o2 + o3);
#pragma unroll
    for (int jj = 0; jj < 4; ++jj) {
      int q = qb * 16 + g * 4 + jj;
      int d = db * 16 + li;
      float x = of[jj];
      short hi = f2bf(x);
      short lo = f2bf(x - bf2f(hi));
      *(unsigned*)&AO2[(qrow0 + q) * 2048 + (size_t)(h * 64 + d) * 2] =
          (unsigned)(unsigned short)hi | ((unsigned)(unsigned short)lo << 16);
    }
    // no 3rd barrier: next head's Pbuf/mlbuf writes are ordered behind its barrier 1
  }

  // ---- head-mean output ----
#pragma unroll
  for (int qcb = 0; qcb < 2; ++qcb)
#pragma unroll
    for (int kb = 0; kb < 8; ++kb) {
      f32x4 v;
#pragma unroll
      for (int jj = 0; jj < 4; ++jj) v[jj] = macc[qcb][kb][jj] * 0.0625f;
      *(f32x4*)&Amean[(qrow0 + qcb * 16 + li) * 1024 + wkv + kb * 16 + 4 * g] = v;
    }
}

// ---------------- launch ----------------
extern "C" void kernel_launch(void* const* d_in, const int* in_sizes, int n_in,
                              void* d_out, int out_size, void* d_ws, size_t ws_size,
                              hipStream_t stream) {
  (void)in_sizes; (void)n_in; (void)out_size; (void)ws_size;
  const float* query     = (const float*)d_in[0];
  const float* key_value = (const float*)d_in[1];
  const float* cluster   = (const float*)d_in[2];
  const float* Wq = (const float*)d_in[3];
  const float* bq = (const float*)d_in[4];
  const float* Wk = (const float*)d_in[5];
  const float* bk = (const float*)d_in[6];
  const float* Wv = (const float*)d_in[7];
  const float* bv = (const float*)d_in[8];
  const float* Wo = (const float*)d_in[9];
  const float* bo = (const float*)d_in[10];

  char* ws = (char*)d_ws;
  short* qb  = (short*)(ws);                  // [8192][1024] bf16 (16 MB)
  short* kvb = (short*)(ws + 16777216);       // [8192][1024]
  short* Wqb = (short*)(ws + 33554432);       // [1024][1024]
  short* Wkb = (short*)(ws + 35651584);
  short* Wvb = (short*)(ws + 37748736);
  short* Wo2 = (short*)(ws + 39845888);       // [1024][2048] duplicated
  short* Qp  = (short*)(ws + 44040192);       // [8192][1024]
  short* Kp  = (short*)(ws + 60817408);       // [8192][1024]
  short* Vtp = (short*)(ws + 77594624);       // [b][h][64][1024]
  short* AO2 = (short*)(ws + 94371840);       // [8192][2048] hi/lo pairs (32 MB)

  float* out_uq = (float*)d_out;              // updated_query [8,1024,1024]
  float* out_am = (float*)d_out + 8388608;    // attn_matrix   [8,1024,1024]

  cvt4<<<8192, 256, 0, stream>>>((const float4v*)query,     (s16x4*)qb,  2097152);
  cvt4<<<8192, 256, 0, stream>>>((const float4v*)key_value, (s16x4*)kvb, 2097152);
  cvt4<<<1024, 256, 0, stream>>>((const float4v*)Wq, (s16x4*)Wqb, 262144);
  cvt4<<<1024, 256, 0, stream>>>((const float4v*)Wk, (s16x4*)Wkb, 262144);
  cvt4<<<1024, 256, 0, stream>>>((const float4v*)Wv, (s16x4*)Wvb, 262144);
  cvt_dup<<<1024, 256, 0, stream>>>((const float4v*)Wo, (s16x8*)Wo2, 262144);

  gemm_nt<0, 1024><<<512, 256, 0, stream>>>(qb,  Wqb, bq, Qp);
  gemm_nt<0, 1024><<<512, 256, 0, stream>>>(kvb, Wkb, bk, Kp);
  gemm_nt<2, 1024><<<512, 256, 0, stream>>>(kvb, Wvb, bv, Vtp);

  attn_fused2<<<dim3(32, 8), 512, 0, stream>>>(Qp, Kp, Vtp, cluster, AO2, out_am);

  gemm_nt<1, 2048><<<512, 256, 0, stream>>>(AO2, Wo2, bo, out_uq);
}

// Round 3
// 496.121 us; speedup vs baseline: 1.5202x; 1.1108x over previous
//
#include <hip/hip_runtime.h>
#include <stdint.h>
#include <stddef.h>

typedef __attribute__((ext_vector_type(4))) float  f32x4;
typedef __attribute__((ext_vector_type(4))) float  float4v;
typedef __attribute__((ext_vector_type(8))) short  s16x8;
typedef __attribute__((ext_vector_type(4))) short  s16x4;
typedef __attribute__((ext_vector_type(2))) unsigned int u32x2;

#define DEV static __device__ __forceinline__

DEV short f2bf(float f) {                 // RNE fp32 -> bf16 (inputs finite)
  unsigned u = __builtin_bit_cast(unsigned, f);
  u = u + 0x7fffu + ((u >> 16) & 1u);
  return (short)(u >> 16);
}
DEV float bf2f(short s) {
  unsigned u = ((unsigned)(unsigned short)s) << 16;
  return __builtin_bit_cast(float, u);
}
DEV f32x4 vmax4(f32x4 a, f32x4 b) {
  f32x4 r;
  r[0] = fmaxf(a[0], b[0]); r[1] = fmaxf(a[1], b[1]);
  r[2] = fmaxf(a[2], b[2]); r[3] = fmaxf(a[3], b[3]);
  return r;
}
DEV void gload16(const void* g, void* l) { // async global->LDS, 16B/lane, dest = base + lane*16
  __builtin_amdgcn_global_load_lds((const __attribute__((address_space(1))) void*)g,
                                   (__attribute__((address_space(3))) void*)l, 16, 0, 0);
}

// ---------------- fp32 -> bf16 converts ----------------
__global__ void cvt4(const float4v* __restrict__ src, s16x4* __restrict__ dst, int n4) {
  int i = blockIdx.x * 256 + threadIdx.x;
  if (i >= n4) return;
  float4v v = src[i];
  s16x4 o; o.x = f2bf(v.x); o.y = f2bf(v.y); o.z = f2bf(v.z); o.w = f2bf(v.w);
  dst[i] = o;
}
// duplicate each element (for hi/lo split K=2048 GEMM): dst[2i]=dst[2i+1]=bf16(src[i])
__global__ void cvt_dup(const float4v* __restrict__ src, s16x8* __restrict__ dst, int n4) {
  int i = blockIdx.x * 256 + threadIdx.x;
  if (i >= n4) return;
  float4v v = src[i];
  s16x8 o;
  o[0] = f2bf(v.x); o[1] = o[0];
  o[2] = f2bf(v.y); o[3] = o[2];
  o[4] = f2bf(v.z); o[5] = o[4];
  o[6] = f2bf(v.w); o[7] = o[6];
  dst[i] = o;
}

// ---------------- GEMM: C[M=8192][N=1024] = A[M][KDIM] @ B[1024][KDIM]^T + bias ----------------
// EPI: 0 = bf16 C;  1 = f32 C;  2 = bf16 C written per-head-transposed (Vt[b,h,d,kv])
template <int EPI, int KDIM>
__global__ __launch_bounds__(256) void gemm_nt(const short* __restrict__ A,
                                               const short* __restrict__ Bw,
                                               const float* __restrict__ bias,
                                               void* __restrict__ Cp) {
  __shared__ __attribute__((aligned(16))) short As[2][128 * 32];
  __shared__ __attribute__((aligned(16))) short Bs[2][128 * 32];
  const int tid = threadIdx.x;
  const int wg  = blockIdx.x;
  const int swz = (wg & 7) * ((int)gridDim.x >> 3) + (wg >> 3);  // XCD-aware (512 % 8 == 0)
  const int bm = swz >> 3, bn = swz & 7;
  const int mbase = bm * 128, nbase = bn * 128;
  const int w = tid >> 6, l = tid & 63;
  const int wm = w >> 1, wn = w & 1;

  auto stage = [&](int buf, int kt) {
#pragma unroll
    for (int j = 0; j < 2; ++j) {
      int cb  = w * 128 + j * 64;       // wave-uniform chunk base
      int ci  = cb + l;                 // this lane's chunk
      int row = ci >> 2, cc = ci & 3;
      int c   = cc ^ ((row >> 1) & 3);  // inverse-swizzled SOURCE chunk
      gload16(A  + (size_t)(mbase + row) * KDIM + kt * 32 + c * 8, &As[buf][cb * 8]);
      gload16(Bw + (size_t)(nbase + row) * KDIM + kt * 32 + c * 8, &Bs[buf][cb * 8]);
    }
  };

  f32x4 acc[4][4];
#pragma unroll
  for (int i = 0; i < 4; ++i)
#pragma unroll
    for (int j = 0; j < 4; ++j) acc[i][j] = (f32x4){0.f, 0.f, 0.f, 0.f};

  const int KSTEPS = KDIM / 32;
  stage(0, 0);
  for (int kt = 0; kt < KSTEPS; ++kt) {
    __syncthreads();                       // drains vmcnt: buf[kt&1] ready
    if (kt + 1 < KSTEPS) stage((kt + 1) & 1, kt + 1);
    const int buf = kt & 1;
    s16x8 af[4], bf[4];
    const int g = l >> 4;
#pragma unroll
    for (int i = 0; i < 4; ++i) {
      int ra = wm * 64 + i * 16 + (l & 15);
      int pa = g ^ ((ra >> 1) & 3);
      af[i] = *(const s16x8*)&As[buf][ra * 32 + pa * 8];
      int rb = wn * 64 + i * 16 + (l & 15);
      int pb = g ^ ((rb >> 1) & 3);
      bf[i] = *(const s16x8*)&Bs[buf][rb * 32 + pb * 8];
    }
#pragma unroll
    for (int i = 0; i < 4; ++i)
#pragma unroll
      for (int j = 0; j < 4; ++j)
        acc[i][j] = __builtin_amdgcn_mfma_f32_16x16x32_bf16(af[i], bf[j], acc[i][j], 0, 0, 0);
  }

  // epilogue
  float bj[4];
#pragma unroll
  for (int j = 0; j < 4; ++j) bj[j] = bias[nbase + wn * 64 + j * 16 + (l & 15)];
#pragma unroll
  for (int i = 0; i < 4; ++i) {
#pragma unroll
    for (int j = 0; j < 4; ++j) {
      int m0 = mbase + wm * 64 + i * 16 + (l >> 4) * 4;
      int n  = nbase + wn * 64 + j * 16 + (l & 15);
      if constexpr (EPI == 0) {
        short* C16 = (short*)Cp;
#pragma unroll
        for (int jj = 0; jj < 4; ++jj)
          C16[(size_t)(m0 + jj) * 1024 + n] = f2bf(acc[i][j][jj] + bj[j]);
      } else if constexpr (EPI == 1) {
        float* Cf = (float*)Cp;
#pragma unroll
        for (int jj = 0; jj < 4; ++jj)
          Cf[(size_t)(m0 + jj) * 1024 + n] = acc[i][j][jj] + bj[j];
      } else {  // per-head transposed V:  Vt[(b*1024 + n)*1024 + kv], n = h*64+d
        short* C16 = (short*)Cp;
        int bb = m0 >> 10, kv = m0 & 1023;
        s16x4 o;
#pragma unroll
        for (int jj = 0; jj < 4; ++jj) o[jj] = f2bf(acc[i][j][jj] + bj[j]);
        *(s16x4*)&C16[((size_t)(bb * 1024 + n)) * 1024 + kv] = o;
      }
    }
  }
}

// ---------------- fused attention v3 ----------------
// Block = (qtile of 32 rows, batch). 8 waves; wave w owns kv slice [128w, 128w+128) for QK^T.
// Swapped QK^T: mfma(K, Q) -> lane holds S for q col (l&15), kv rows wkv+kb*16+4*(l>>4)+jj.
// Cluster preloaded ONCE into registers (log2-domain), head-invariant lane ownership.
// Softmax fully in log2 domain. Cross-wave (m,l) via padded mlbuf (stride 20 -> 2-way max).
// P (bf16, normalized) -> Pbuf LDS. PV kv-split: wave (db=w&3, kvh=w>>2) computes BOTH
// q-halves over its kv half (V read exactly once per block), then 8KB f32x4 LDS exchange.
// Head-mean accumulated in registers; 3 barriers/head.
__global__ __launch_bounds__(512, 2) void attn_fused3(const short* __restrict__ Qp,
                                                      const short* __restrict__ Kp,
                                                      const short* __restrict__ Vt,
                                                      const float* __restrict__ cluster,
                                                      short* __restrict__ AO2,
                                                      float* __restrict__ Amean) {
  constexpr int PSTR = 1032;  // bf16 row stride (uniform bank spread for b128 reads)
  __shared__ __attribute__((aligned(16))) short Pbuf[32 * PSTR];  // 66 KB
  __shared__ float mlbuf[32][20];                                 // 2.5 KB, 2-way max
  __shared__ __attribute__((aligned(16))) f32x4 obuf[4][2][16][4]; // 8 KB PV exchange
  const int tid = threadIdx.x;
  const int b = blockIdx.y, qt = blockIdx.x;
  const int w = tid >> 6, l = tid & 63;
  const int li = l & 15, g = l >> 4;
  const int wkv = w * 128;
  const int db = w & 3, kvh = w >> 2;  // PV: d-subtile, kv-half
  const float LOG2E = 1.4426950408889634f;
  const float scaleL = 0.125f * LOG2E;  // (1/sqrt(64)) * log2(e)

  const size_t qrow0 = (size_t)(b * 1024 + qt * 32);
  const size_t krow0 = (size_t)(b * 1024);

  // cluster preload (log2 domain) + head-mean accumulators: head-invariant cells
  f32x4 clv[2][8], macc[2][8];
#pragma unroll
  for (int qcb = 0; qcb < 2; ++qcb) {
    const float* clp = cluster + (qrow0 + qcb * 16 + li) * 1024 + wkv + 4 * g;
#pragma unroll
    for (int kb = 0; kb < 8; ++kb) {
      f32x4 cl = *(const f32x4*)(clp + kb * 16);
      clv[qcb][kb] = cl * LOG2E;
      macc[qcb][kb] = (f32x4){0.f, 0.f, 0.f, 0.f};
    }
  }

  for (int h = 0; h < 16; ++h) {
    // ---- QK^T (swapped): acc[qcb][kb] over kv slice ----
    s16x8 qf[2][2];
#pragma unroll
    for (int qcb = 0; qcb < 2; ++qcb)
#pragma unroll
      for (int kc = 0; kc < 2; ++kc)
        qf[qcb][kc] = *(const s16x8*)&Qp[(qrow0 + qcb * 16 + li) * 1024 + h * 64 + kc * 32 + g * 8];

    f32x4 acc[2][8];
#pragma unroll
    for (int a = 0; a < 2; ++a)
#pragma unroll
      for (int kb = 0; kb < 8; ++kb) acc[a][kb] = (f32x4){0.f, 0.f, 0.f, 0.f};

#pragma unroll
    for (int quarter = 0; quarter < 4; ++quarter) {
      s16x8 kf[4];
#pragma unroll
      for (int i = 0; i < 4; ++i) {
        int kb = quarter * 2 + (i >> 1), kc = i & 1;
        kf[i] = *(const s16x8*)&Kp[(krow0 + wkv + kb * 16 + li) * 1024 + h * 64 + kc * 32 + g * 8];
      }
#pragma unroll
      for (int i = 0; i < 4; ++i) {
        int kb = quarter * 2 + (i >> 1), kc = i & 1;
#pragma unroll
        for (int qcb = 0; qcb < 2; ++qcb)
          acc[qcb][kb] = __builtin_amdgcn_mfma_f32_16x16x32_bf16(kf[i], qf[qcb][kc], acc[qcb][kb], 0, 0, 0);
      }
    }

    // ---- per-wave softmax over the 128-kv slice (log2 domain) ----
    float mw[2], lw[2];
#pragma unroll
    for (int qcb = 0; qcb < 2; ++qcb) {
#pragma unroll
      for (int kb = 0; kb < 8; ++kb)
        acc[qcb][kb] = acc[qcb][kb] * scaleL + clv[qcb][kb];
      f32x4 mx = acc[qcb][0];
#pragma unroll
      for (int kb = 1; kb < 8; ++kb) mx = vmax4(mx, acc[qcb][kb]);
      float m = fmaxf(fmaxf(mx[0], mx[1]), fmaxf(mx[2], mx[3]));
      m = fmaxf(m, __shfl_xor(m, 16, 64));
      m = fmaxf(m, __shfl_xor(m, 32, 64));
      f32x4 s4 = (f32x4){0.f, 0.f, 0.f, 0.f};
#pragma unroll
      for (int kb = 0; kb < 8; ++kb) {
        f32x4 e;
#pragma unroll
        for (int jj = 0; jj < 4; ++jj) e[jj] = __builtin_amdgcn_exp2f(acc[qcb][kb][jj] - m);
        acc[qcb][kb] = e;
        s4 += e;
      }
      float s = (s4[0] + s4[1]) + (s4[2] + s4[3]);
      s += __shfl_xor(s, 16, 64);
      s += __shfl_xor(s, 32, 64);
      mw[qcb] = m; lw[qcb] = s;
    }
    if (l < 16) {
#pragma unroll
      for (int qcb = 0; qcb < 2; ++qcb) {
        mlbuf[qcb * 16 + l][2 * w]     = mw[qcb];
        mlbuf[qcb * 16 + l][2 * w + 1] = lw[qcb];
      }
    }
    __syncthreads();  // B1: (m,l) partials visible

    // ---- combine + normalize + write P (bf16) + head-mean accumulate ----
#pragma unroll
    for (int qcb = 0; qcb < 2; ++qcb) {
      const int q = qcb * 16 + li;
      float m = mlbuf[q][0];
#pragma unroll
      for (int j = 1; j < 8; ++j) m = fmaxf(m, mlbuf[q][2 * j]);
      float lt = 0.f;
#pragma unroll
      for (int j = 0; j < 8; ++j) lt += mlbuf[q][2 * j + 1] * __builtin_amdgcn_exp2f(mlbuf[q][2 * j] - m);
      const float c = __builtin_amdgcn_exp2f(mw[qcb] - m) / lt;
#pragma unroll
      for (int kb = 0; kb < 8; ++kb) {
        f32x4 p = acc[qcb][kb] * c;
        macc[qcb][kb] += p;
        unsigned u0 = (unsigned)(unsigned short)f2bf(p[0]) | ((unsigned)(unsigned short)f2bf(p[1]) << 16);
        unsigned u1 = (unsigned)(unsigned short)f2bf(p[2]) | ((unsigned)(unsigned short)f2bf(p[3]) << 16);
        u32x2 uu; uu[0] = u0; uu[1] = u1;
        *(u32x2*)&Pbuf[q * PSTR + wkv + kb * 16 + 4 * g] = uu;
      }
    }
    __syncthreads();  // B2: full P tile visible

    // ---- PV kv-split: wave (db, kvh) does both q-halves over kv [512*kvh, 512*kvh+512) ----
    f32x4 o0a = (f32x4){0.f,0.f,0.f,0.f}, o0b = o0a, o1a = o0a, o1b = o0a;
    {
      const short* vb = Vt + ((size_t)((b * 16 + h) * 64 + db * 16 + li)) * 1024 + kvh * 512 + g * 8;
      const short* p0 = &Pbuf[li * PSTR + kvh * 512 + g * 8];
      const short* p1 = &Pbuf[(16 + li) * PSTR + kvh * 512 + g * 8];
#pragma unroll
      for (int kc = 0; kc < 16; kc += 2) {
        s16x8 vfa = *(const s16x8*)(vb + kc * 32);
        s16x8 vfb = *(const s16x8*)(vb + kc * 32 + 32);
        s16x8 pa0 = *(const s16x8*)(p0 + kc * 32);
        s16x8 pb0 = *(const s16x8*)(p0 + kc * 32 + 32);
        s16x8 pa1 = *(const s16x8*)(p1 + kc * 32);
        s16x8 pb1 = *(const s16x8*)(p1 + kc * 32 + 32);
        o0a = __builtin_amdgcn_mfma_f32_16x16x32_bf16(pa0, vfa, o0a, 0, 0, 0);
        o1a = __builtin_amdgcn_mfma_f32_16x16x32_bf16(pa1, vfa, o1a, 0, 0, 0);
        o0b = __builtin_amdgcn_mfma_f32_16x16x32_bf16(pb0, vfb, o0b, 0, 0, 0);
        o1b = __builtin_amdgcn_mfma_f32_16x16x32_bf16(pb1, vfb, o1b, 0, 0, 0);
      }
    }
    f32x4 of0 = o0a + o0b, of1 = o1a + o1b;
    // exchange the half this wave does NOT finalize
    if (kvh == 1) obuf[db][0][li][g] = of0;
    else          obuf[db][1][li][g] = of1;
    __syncthreads();  // B3: partials visible
    {
      f32x4 of = (kvh == 0) ? (of0 + obuf[db][0][li][g]) : (of1 + obuf[db][1][li][g]);
      const int qb = kvh;
#pragma unroll
      for (int jj = 0; jj < 4; ++jj) {
        int q = qb * 16 + g * 4 + jj;
        int d = db * 16 + li;
        float x = of[jj];
        short hi = f2bf(x);
        short lo = f2bf(x - bf2f(hi));
        *(unsigned*)&AO2[(qrow0 + q) * 2048 + (size_t)(h * 64 + d) * 2] =
            (unsigned)(unsigned short)hi | ((unsigned)(unsigned short)lo << 16);
      }
    }
    // next head's mlbuf/Pbuf writes are behind its B1/B2; obuf rewrite behind next B2.
  }

  // ---- head-mean output ----
#pragma unroll
  for (int qcb = 0; qcb < 2; ++qcb)
#pragma unroll
    for (int kb = 0; kb < 8; ++kb)
      *(f32x4*)&Amean[(qrow0 + qcb * 16 + li) * 1024 + wkv + kb * 16 + 4 * g] = macc[qcb][kb] * 0.0625f;
}

// ---------------- launch ----------------
extern "C" void kernel_launch(void* const* d_in, const int* in_sizes, int n_in,
                              void* d_out, int out_size, void* d_ws, size_t ws_size,
                              hipStream_t stream) {
  (void)in_sizes; (void)n_in; (void)out_size; (void)ws_size;
  const float* query     = (const float*)d_in[0];
  const float* key_value = (const float*)d_in[1];
  const float* cluster   = (const float*)d_in[2];
  const float* Wq = (const float*)d_in[3];
  const float* bq = (const float*)d_in[4];
  const float* Wk = (const float*)d_in[5];
  const float* bk = (const float*)d_in[6];
  const float* Wv = (const float*)d_in[7];
  const float* bv = (const float*)d_in[8];
  const float* Wo = (const float*)d_in[9];
  const float* bo = (const float*)d_in[10];

  char* ws = (char*)d_ws;
  short* qb  = (short*)(ws);                  // [8192][1024] bf16 (16 MB)
  short* kvb = (short*)(ws + 16777216);       // [8192][1024]
  short* Wqb = (short*)(ws + 33554432);       // [1024][1024]
  short* Wkb = (short*)(ws + 35651584);
  short* Wvb = (short*)(ws + 37748736);
  short* Wo2 = (short*)(ws + 39845888);       // [1024][2048] duplicated
  short* Qp  = (short*)(ws + 44040192);       // [8192][1024]
  short* Kp  = (short*)(ws + 60817408);       // [8192][1024]
  short* Vtp = (short*)(ws + 77594624);       // [b][h][64][1024]
  short* AO2 = (short*)(ws + 94371840);       // [8192][2048] hi/lo pairs (32 MB)

  float* out_uq = (float*)d_out;              // updated_query [8,1024,1024]
  float* out_am = (float*)d_out + 8388608;    // attn_matrix   [8,1024,1024]

  cvt4<<<8192, 256, 0, stream>>>((const float4v*)query,     (s16x4*)qb,  2097152);
  cvt4<<<8192, 256, 0, stream>>>((const float4v*)key_value, (s16x4*)kvb, 2097152);
  cvt4<<<1024, 256, 0, stream>>>((const float4v*)Wq, (s16x4*)Wqb, 262144);
  cvt4<<<1024, 256, 0, stream>>>((const float4v*)Wk, (s16x4*)Wkb, 262144);
  cvt4<<<1024, 256, 0, stream>>>((const float4v*)Wv, (s16x4*)Wvb, 262144);
  cvt_dup<<<1024, 256, 0, stream>>>((const float4v*)Wo, (s16x8*)Wo2, 262144);

  gemm_nt<0, 1024><<<512, 256, 0, stream>>>(qb,  Wqb, bq, Qp);
  gemm_nt<0, 1024><<<512, 256, 0, stream>>>(kvb, Wkb, bk, Kp);
  gemm_nt<2, 1024><<<512, 256, 0, stream>>>(kvb, Wvb, bv, Vtp);

  attn_fused3<<<dim3(32, 8), 512, 0, stream>>>(Qp, Kp, Vtp, cluster, AO2, out_am);

  gemm_nt<1, 2048><<<512, 256, 0, stream>>>(AO2, Wo2, bo, out_uq);
}